// Round 1
// baseline (74.333 us; speedup 1.0000x reference)
//
#include <hip/hip_runtime.h>

// Gravity field: F[b,i,:] = G * m_i * mask_i * sum_j (m_j*mask_j) * (p_j - p_i) / max(|p_j-p_i|, 1e-4)^3
// Diagonal term is identically zero because diff == 0 exactly (no branch needed).
// max(sqrt(r2), eps) == sqrt(max(r2, eps*eps)) -> single rsqrtf + clamp.

#define TI 256   // bodies-i per block (= block size)
#define TJ 128   // bodies-j per block (staged in LDS)

__global__ __launch_bounds__(TI) void gravity_kernel(
    const float* __restrict__ pos,    // (B, N, 3)
    const float* __restrict__ mass,   // (B, N, 1)
    const float* __restrict__ Gp,     // (1,)
    const float* __restrict__ mask,   // (B, N)
    float* __restrict__ out,          // (B, N, 3) -- pre-zeroed
    int N, int jsplit)
{
    __shared__ float4 sj[TJ];

    const int tiles_i = N / TI;
    const int per_b   = tiles_i * jsplit;
    const int bid     = blockIdx.x;
    const int b       = bid / per_b;
    const int rem     = bid - b * per_b;
    const int it      = rem / jsplit;
    const int jc      = rem - it * jsplit;
    const int tid     = threadIdx.x;
    const int i       = it * TI + tid;

    const float* posb  = pos  + (size_t)b * N * 3;
    const float* massb = mass + (size_t)b * N;
    const float* maskb = mask + (size_t)b * N;

    // Stage j-tile: position + (mass*mask) packed as float4.
    if (tid < TJ) {
        const int j = jc * TJ + tid;
        float4 v;
        v.x = posb[j * 3 + 0];
        v.y = posb[j * 3 + 1];
        v.z = posb[j * 3 + 2];
        v.w = massb[j] * maskb[j];
        sj[tid] = v;
    }

    const float pix = posb[i * 3 + 0];
    const float piy = posb[i * 3 + 1];
    const float piz = posb[i * 3 + 2];
    const float wi  = Gp[0] * massb[i] * maskb[i];

    __syncthreads();

    float fx = 0.f, fy = 0.f, fz = 0.f;
#pragma unroll 8
    for (int k = 0; k < TJ; ++k) {
        const float4 pj = sj[k];          // broadcast LDS read (all lanes same addr)
        const float dx = pj.x - pix;
        const float dy = pj.y - piy;
        const float dz = pj.z - piz;
        float r2 = fmaf(dx, dx, fmaf(dy, dy, dz * dz));
        r2 = fmaxf(r2, 1e-8f);            // = (max(dist, 1e-4))^2
        const float ir  = rsqrtf(r2);
        const float s   = pj.w * (ir * ir * ir);
        fx = fmaf(s, dx, fx);
        fy = fmaf(s, dy, fy);
        fz = fmaf(s, dz, fz);
    }

    float* o = out + ((size_t)b * N + i) * 3;
    atomicAdd(&o[0], fx * wi);
    atomicAdd(&o[1], fy * wi);
    atomicAdd(&o[2], fz * wi);
}

extern "C" void kernel_launch(void* const* d_in, const int* in_sizes, int n_in,
                              void* d_out, int out_size, void* d_ws, size_t ws_size,
                              hipStream_t stream)
{
    const float* pos  = (const float*)d_in[0];
    const float* mass = (const float*)d_in[1];
    const float* Gp   = (const float*)d_in[2];
    const float* mask = (const float*)d_in[3];
    float* out = (float*)d_out;

    const int N = 4096;                 // fixed problem shape
    const int B = in_sizes[3] / N;      // mask is (B, N)
    const int jsplit = N / TJ;          // 32 j-chunks per batch/i-tile

    // d_out is re-poisoned to 0xAA before every launch -> zero it (capture-safe).
    hipMemsetAsync(d_out, 0, (size_t)out_size * sizeof(float), stream);

    const int grid = B * (N / TI) * jsplit;   // 2 * 16 * 32 = 1024 blocks
    gravity_kernel<<<grid, TI, 0, stream>>>(pos, mass, Gp, mask, out, N, jsplit);
}